// Round 1
// 167.259 us; speedup vs baseline: 1.0155x; 1.0155x over previous
//
#include <hip/hip_runtime.h>

#define HW_   5776   // 76*76
#define W_    76
#define NA_   3      // anchors
#define NB_   16     // batch
#define NPOS  (NB_ * NA_ * HW_)   // 277248 total positions
#define NWG   (NPOS / 128)        // 2166 blocks, exact
#define ROWQ  21     // odd float4 stride per LDS row -> even bank-group spread, no pad

__device__ __forceinline__ float sigmoidf_(float x) {
    return 1.0f / (1.0f + __expf(-x));
}

// Two lanes per position (40/40 class split). Conf output staged through a
// per-wave LDS transpose so global stores are fully coalesced. The staging is
// done in TWO position-half rounds (16 rows each) so the per-block LDS drops
// from 48 KB -> 21 KB: occupancy rises from 3 to 7 blocks/CU (12 -> 28
// waves/CU), which is what hides the one big vmcnt stall each wave takes on
// its 45-load batch. Per-wave buffer + in-order DS pipe => no __syncthreads;
// round-1 writes cannot pass round-0 reads (same-wave DS ordering + aliasing).
__global__ __launch_bounds__(256, 7) void yolo_kernel(const float* __restrict__ in,
                                                      float* __restrict__ out) {
    __shared__ float4 lds[4][16 * ROWQ];   // 5376 B per wave, 21504 B per block

    // XCD-chunked bijective remap (2166 % 8 = 6 -> need the bijective form):
    // consecutive position-blocks land on the SAME XCD/L2, so the 64B-shared
    // boundary lines (channel stride 23104 B == 64 mod 128) are fetched once.
    constexpr int Q = NWG >> 3;   // 270
    constexpr int R = NWG & 7;    // 6
    const int xcd = blockIdx.x & 7;
    const int seq = blockIdx.x >> 3;
    const int bid = (xcd < R ? xcd * (Q + 1) : R * (Q + 1) + (xcd - R) * Q) + seq;

    const int tid   = threadIdx.x;
    const int lane  = tid & 63;
    const int wv    = tid >> 6;           // wave within block (0..3)
    const int half  = lane >> 5;          // 0 or 1
    const int pos   = lane & 31;          // wave-local position index
    const int Pbase = bid * 128 + wv * 32;  // first position of this wave
    const int P     = Pbase + pos;

    const int slab = P / HW_;             // = b*3 + a   (0..47)
    const int p    = P - slab * HW_;      // position in 76x76 plane
    const int a    = slab % NA_;

    const float aw3[3] = {1.5f, 2.375f, 5.0f};   // [12,19,40]/8
    const float ah3[3] = {2.0f, 4.5f, 3.5f};     // [16,36,28]/8
    const float invW = 1.0f / 76.0f;

    const float* src = in + (size_t)slab * (85 * (size_t)HW_) + p;

    // box channels 0..4 (same addresses across halves -> coalescer-merged)
    const float b0 = src[0 * (size_t)HW_];
    const float b1 = src[1 * (size_t)HW_];
    const float b2 = src[2 * (size_t)HW_];
    const float b3 = src[3 * (size_t)HW_];
    const float b4 = src[4 * (size_t)HW_];

    // this half's 40 class channels (each load: 2x contiguous 128B segments)
    const float* csrc = src + (size_t)(5 + half * 40) * HW_;
    float v[40];
#pragma unroll
    for (int c = 0; c < 40; ++c) v[c] = csrc[(size_t)c * HW_];

    const int x = p % W_;
    const int y = p / W_;
    const float bx  = (sigmoidf_(b0) + (float)x) * invW;
    const float by  = (sigmoidf_(b1) + (float)y) * invW;
    const float bw  = __expf(b2) * (aw3[a] * invW);
    const float bh  = __expf(b3) * (ah3[a] * invW);
    const float det = sigmoidf_(b4);

    // softmax across 80 classes, split 40/40 over the lane pair
    float m = v[0];
#pragma unroll
    for (int c = 1; c < 40; ++c) m = fmaxf(m, v[c]);
    m = fmaxf(m, __shfl_xor(m, 32));
    float s = 0.0f;
#pragma unroll
    for (int c = 0; c < 40; ++c) { v[c] = __expf(v[c] - m); s += v[c]; }
    s += __shfl_xor(s, 32);
    const float scale = det / s;

    // boxes: [B][A*HW][4]; row index == P; coalesced 512B per wave
    if (half == 0) {
        ((float4*)out)[P] = make_float4(bx, by, bw, bh);
    }

    // ---- conf: stage + drain in two position-half rounds ----
    // Round r covers wave-local positions [16r, 16r+16). Stage: the 32 lanes
    // owning those positions (16 from each half) write their 10 quads at
    // row*21 + k  (odd stride -> bank-group (5*row + 2*half + i) & 7, even
    // spread). Drain: all 64 lanes copy the 320 float4s to a fully
    // contiguous 5 KB global span (1 KB per store instruction).
    float4* conf4 = (float4*)out + NPOS + (size_t)Pbase * 20;
    const int row = pos & 15;
#pragma unroll
    for (int r = 0; r < 2; ++r) {
        if ((pos >> 4) == r) {
#pragma unroll
            for (int i = 0; i < 10; ++i) {
                const int k = half * 10 + i;
                lds[wv][row * ROWQ + k] = make_float4(v[4 * i]     * scale,
                                                      v[4 * i + 1] * scale,
                                                      v[4 * i + 2] * scale,
                                                      v[4 * i + 3] * scale);
            }
        }
#pragma unroll
        for (int i = 0; i < 5; ++i) {
            const int f     = i * 64 + lane;      // 0..319
            const int pos_r = f / 20;             // 0..15  (row in this round)
            const int k_r   = f - pos_r * 20;     // 0..19
            conf4[r * 320 + f] = lds[wv][pos_r * ROWQ + k_r];
        }
    }
}

extern "C" void kernel_launch(void* const* d_in, const int* in_sizes, int n_in,
                              void* d_out, int out_size, void* d_ws, size_t ws_size,
                              hipStream_t stream) {
    const float* in = (const float*)d_in[0];
    float* out = (float*)d_out;
    yolo_kernel<<<NWG, 256, 0, stream>>>(in, out);
}